// Round 15
// baseline (746.492 us; speedup 1.0000x reference)
//
#include <hip/hip_runtime.h>
#include <cstdint>
#include <cstddef>

#define BATCH 256
#define SEQ   512
#define HID   512
#define VOCAB 128

#define BT     16              // batch rows per block
#define HSTRB  528             // h-buffer row stride in BYTES (512 + 16, 16B-aligned)
#define LOG2E2 2.88539008177793f   // 2*log2(e): e^{2z} = 2^(z*LOG2E2), baked into E and fq

typedef __attribute__((ext_vector_type(4))) int   i32x4;
typedef __attribute__((ext_vector_type(4))) float f32x4;

// ---- fused prologue: eproj (blocks 0..15) + abs-max partials (blocks 16..55) ----
// E is written PERMUTED within each 64-col group: true unit u = jj*16+nn stored at
// addr nn*4+jj, so the rnn epilogue reads its 4 j-values as ONE float4.
__global__ __launch_bounds__(512)
void prep_kernel(const float* __restrict__ emb,
                 const float* __restrict__ W_ih,
                 const float* __restrict__ b_ih,
                 const float* __restrict__ b_hh,
                 const float* __restrict__ W_hh,
                 const float* __restrict__ W_ho,
                 float* __restrict__ E,
                 float* __restrict__ parts) {
  __shared__ float es[8][64];     // eproj staging
  __shared__ float wmax[8];       // maxred wave partials
  const int bid = blockIdx.x;
  const int tid = threadIdx.x;

  if (bid < 16) {                 // ---- eproj ----
    const int j = tid;            // true unit index
    const int v0 = bid * 8;
    float acc[8];
#pragma unroll
    for (int v = 0; v < 8; ++v) acc[v] = 0.f;
    for (int k0 = 0; k0 < HID; k0 += 64) {
      __syncthreads();
      es[j >> 6][j & 63] = emb[(size_t)(v0 + (j >> 6)) * HID + k0 + (j & 63)];
      __syncthreads();
#pragma unroll 8
      for (int kk = 0; kk < 64; ++kk) {
        const float w = W_ih[(size_t)(k0 + kk) * HID + j];
#pragma unroll
        for (int v = 0; v < 8; ++v) acc[v] += es[v][kk] * w;
      }
    }
    const float bias = b_ih[j] + b_hh[j];
    // permuted store address: group | nn*4 | jj
    const int pj = (j & ~63) | ((j & 15) << 2) | ((j >> 4) & 3);
#pragma unroll
    for (int v = 0; v < 8; ++v)
      E[(size_t)(v0 + v) * HID + pj] = (acc[v] + bias) * LOG2E2;
  } else {                        // ---- abs-max partial ----
    const bool hh = (bid < 48);
    const float* src = hh ? W_hh : W_ho;
    const int n     = hh ? HID * HID : HID * VOCAB;
    const int base  = hh ? (bid - 16) : (bid - 48);
    const int nb    = hh ? 32 : 8;
    float m = 0.f;
    for (int i = base * 512 + tid; i < n; i += nb * 512)
      m = fmaxf(m, fabsf(src[i]));
#pragma unroll
    for (int off = 32; off; off >>= 1)
      m = fmaxf(m, __shfl_down(m, off));
    if ((tid & 63) == 0) wmax[tid >> 6] = m;
    __syncthreads();
    if (tid == 0) {
      float mm = wmax[0];
#pragma unroll
      for (int w = 1; w < 8; ++w) mm = fmaxf(mm, wmax[w]);
      parts[bid - 16] = mm;       // slots 0..31 = W_hh, 32..39 = W_ho
    }
  }
}

// Pack [W_hh | W_ho] (512 x 640) into i8 MFMA B-fragments for 16x16x64, with the
// k-axis PERMUTED to match the dword-packed h storage: storage address c within
// each 64-k block holds true unit (c&3)*16 + (c>>2). Fragment slot (q,i) is
// address c = q*16+i  =>  k_true = kt8*64 + (i&3)*16 + q*4 + (i>>2).
__global__ void pack8_kernel(const float* __restrict__ W_hh,
                             const float* __restrict__ W_ho,
                             const float* __restrict__ parts,
                             float* __restrict__ scf,        // [0]=max|W_hh|, [1]=max|W_ho|
                             uint4* __restrict__ Wf8) {
  const int f = blockIdx.x;            // 0..319 (40 nt * 8 kt8)
  const int nt = f >> 3, kt8 = f & 7;
  const int lane = threadIdx.x;
  const int q = lane >> 4, nn = lane & 15;
  const int n = nt * 16 + nn;

  float phh = parts[lane & 31];
#pragma unroll
  for (int off = 16; off; off >>= 1) phh = fmaxf(phh, __shfl_down(phh, off));
  const float s_hh = __shfl(phh, 0);
  float pho = parts[32 + (lane & 7)];
#pragma unroll
  for (int off = 4; off; off >>= 1) pho = fmaxf(pho, __shfl_down(pho, off));
  const float s_ho = __shfl(pho, 0);
  if (f == 0 && lane == 0) { scf[0] = s_hh; scf[1] = s_ho; }

  const float inv = 127.f / ((nt < 32) ? s_hh : s_ho);
  union { int8_t b[16]; uint4 u; } val;
#pragma unroll
  for (int i = 0; i < 16; ++i) {
    const int k = kt8 * 64 + (i & 3) * 16 + q * 4 + (i >> 2);   // k-permutation
    const float w = (n < HID) ? W_hh[(size_t)k * HID + n]
                              : W_ho[(size_t)k * VOCAB + (n - HID)];
    val.b[i] = (int8_t)__float2int_rn(w * inv);
  }
  Wf8[(size_t)f * 64 + lane] = val.u;
}

// Recurrence: h_t = tanh(E[x_t] + h_{t-1} @ W_hh), all-i8 MFMA.  [r13 structure]
// NEW vs r13 (SAFE subset of the r14 bundle — pk-f32 inline asm dropped, it was
// the prime suspect for r14's correctness failure):
//  1. dword byte-pack via 3x v_perm_b32 (ISA-verified byte-select, same bytes).
//  2. persistent x token pointers (uniform clamped advance) — no per-step idx math.
//  3. zero-seeded first MFMA (C-in = pinned zero4) — no per-step acc zero-init.
__global__ __launch_bounds__(512, 2)
void rnn_kernel(const int* __restrict__ x,
                const float* __restrict__ E,
                const uint4* __restrict__ Wf8,
                const float* __restrict__ sc,
                int8_t* __restrict__ Hall,
                float* __restrict__ outH) {
  __shared__ __align__(16) int8_t hbuf[2][BT][HSTRB];   // 16.9 KB double-buffered

  const int tid = threadIdx.x;
  const int wave = tid >> 6, lane = tid & 63;
  const int q = lane >> 4, nn = lane & 15;
  const int r0 = blockIdx.x * BT;
  const float fq = sc[0] * (LOG2E2 / (127.f * 127.f));  // acc -> 2log2e * preact
  const i32x4 zero4 = {0, 0, 0, 0};

  // 4 weight strips per wave (nt = wave*4+j): j<2 in AGPR, j>=2 in VGPR; pinned.
  i32x4 wa[2][8], wv[2][8];
  {
    const uint4* wb = Wf8 + lane;
#pragma unroll
    for (int j = 0; j < 2; ++j)
#pragma unroll
      for (int kt = 0; kt < 8; ++kt)
        wa[j][kt] = __builtin_bit_cast(i32x4, wb[(size_t)((wave * 4 + j) * 8 + kt) * 64]);
#pragma unroll
    for (int j = 0; j < 2; ++j)
#pragma unroll
      for (int kt = 0; kt < 8; ++kt)
        wv[j][kt] = __builtin_bit_cast(i32x4, wb[(size_t)((wave * 4 + 2 + j) * 8 + kt) * 64]);
  }
#pragma unroll
  for (int j = 0; j < 2; ++j)
#pragma unroll
    for (int kt = 0; kt < 8; ++kt)
      asm volatile("" : "+a"(wa[j][kt]));
#pragma unroll
  for (int j = 0; j < 2; ++j)
#pragma unroll
    for (int kt = 0; kt < 8; ++kt)
      asm volatile("" : "+v"(wv[j][kt]));

  // persistent Hall write pointers (advance by HID bytes/step)
  uint32_t* hallp[4];
#pragma unroll
  for (int r = 0; r < 4; ++r)
    hallp[r] = (uint32_t*)(Hall + (size_t)(r0 + q * 4 + r) * SEQ * HID + wave * 64 + nn * 4);

  // persistent token pointers; tokc = x[.][0], xp then points at the NEXT token
  const int* xp[4];
  int tokc[4];
#pragma unroll
  for (int r = 0; r < 4; ++r) {
    xp[r] = x + (size_t)(r0 + q * 4 + r) * SEQ;
    tokc[r] = xp[r][0];
    xp[r] += 1;
  }

  int cur = 0;
  for (int t = 0; t < SEQ; ++t) {
    int tokn[4];
#pragma unroll
    for (int r = 0; r < 4; ++r) tokn[r] = *xp[r];
    const int adv = (t + 2 < SEQ) ? 1 : 0;   // clamp at SEQ-1 (uniform)
#pragma unroll
    for (int r = 0; r < 4; ++r) xp[r] += adv;

    // E' rows: ONE float4 per token (permuted storage: addr nn*4+j holds unit j*16+nn)
    f32x4 ev4[4];
#pragma unroll
    for (int r = 0; r < 4; ++r)
      ev4[r] = *(const f32x4*)&E[(size_t)tokc[r] * HID + wave * 64 + nn * 4];

    i32x4 acc[4];
    if (t > 0) {
      {  // kt = 0 seeds from the pinned zero4 — no per-step acc zero-init
        const i32x4 a = *(const i32x4*)&hbuf[cur][nn][q * 16];
        acc[0] = __builtin_amdgcn_mfma_i32_16x16x64_i8(a, wa[0][0], zero4, 0, 0, 0);
        acc[1] = __builtin_amdgcn_mfma_i32_16x16x64_i8(a, wa[1][0], zero4, 0, 0, 0);
        acc[2] = __builtin_amdgcn_mfma_i32_16x16x64_i8(a, wv[0][0], zero4, 0, 0, 0);
        acc[3] = __builtin_amdgcn_mfma_i32_16x16x64_i8(a, wv[1][0], zero4, 0, 0, 0);
      }
#pragma unroll
      for (int kt = 1; kt < 8; ++kt) {
        const i32x4 a = *(const i32x4*)&hbuf[cur][nn][kt * 64 + q * 16];
        acc[0] = __builtin_amdgcn_mfma_i32_16x16x64_i8(a, wa[0][kt], acc[0], 0, 0, 0);
        acc[1] = __builtin_amdgcn_mfma_i32_16x16x64_i8(a, wa[1][kt], acc[1], 0, 0, 0);
        acc[2] = __builtin_amdgcn_mfma_i32_16x16x64_i8(a, wv[0][kt], acc[2], 0, 0, 0);
        acc[3] = __builtin_amdgcn_mfma_i32_16x16x64_i8(a, wv[1][kt], acc[3], 0, 0, 0);
      }
    } else {
#pragma unroll
      for (int j = 0; j < 4; ++j) acc[j] = zero4;
    }
    // NO barrier here: epilogue writes go to buf[cur^1] (disjoint from reads of buf[cur])

    // epilogue (r-outer, j-inner): zp = acc*fq + ev4; e=2^zp; rr=rcp(e+1);
    // h127 = fma(-254, rr, 127); 4 low bytes packed via 3x v_perm_b32.
#pragma unroll
    for (int r = 0; r < 4; ++r) {
      const int m = q * 4 + r;
      int ii[4];
#pragma unroll
      for (int j = 0; j < 4; ++j) {
        const float zp = fmaf((float)acc[j][r], fq, ev4[r][j]);
        float e;
        asm("v_exp_f32 %0, %1" : "=v"(e) : "v"(zp));     // e = 2^zp = e^{2z}
        const float rr = __builtin_amdgcn_rcpf(e + 1.f);
        ii[j] = __float2int_rn(fmaf(-254.f, rr, 127.f));
        if (t == SEQ - 1)   // exact fp32 h at TRUE col (unpermuted out layout)
          outH[(size_t)(r0 + m) * HID + wave * 64 + j * 16 + nn] = fmaf(-2.f, rr, 1.f);
      }
      // byte j of hp = low byte of ii[j]  (v_perm_b32: sel k<4 -> S1 byte k, k>=4 -> S0 byte k-4)
      const uint32_t t01 = __builtin_amdgcn_perm((uint32_t)ii[1], (uint32_t)ii[0], 0x00000400u);
      const uint32_t t23 = __builtin_amdgcn_perm((uint32_t)ii[3], (uint32_t)ii[2], 0x00000400u);
      const uint32_t hp  = __builtin_amdgcn_perm(t23, t01, 0x05040100u);
      *(uint32_t*)&hbuf[cur ^ 1][m][wave * 64 + nn * 4] = hp;
      *hallp[r] = hp;
      hallp[r] += HID / 4;
    }
    // single per-step sync: drain LDS writes, publish buf[cur^1]; Hall stores keep flying
    asm volatile("s_waitcnt lgkmcnt(0)\n\ts_barrier" ::: "memory");

#pragma unroll
    for (int r = 0; r < 4; ++r) tokc[r] = tokn[r];
    cur ^= 1;
  }
}

// Y[b,s,:] = (f_hh_h * f_ho) * (h_i8 @ Who_i8) + b_o  — fully parallel, i8 MFMA.
// Reads Hall's permuted storage; Wf8's W_ho fragments carry the matching k-perm.
__global__ __launch_bounds__(256)
void ygemm_kernel(const int8_t* __restrict__ Hall,
                  const uint4* __restrict__ Wf8,
                  const float* __restrict__ sc,
                  const float* __restrict__ b_o,
                  float* __restrict__ out) {
  const int tid = threadIdx.x;
  const int wave = tid >> 6, lane = tid & 63;
  const int q = lane >> 4, nn = lane & 15;
  const size_t row0 = (size_t)blockIdx.x * 64 + (size_t)wave * 16;
  const float f = sc[1] * (1.f / (127.f * 127.f));
  i32x4 acc[8];
#pragma unroll
  for (int i = 0; i < 8; ++i) acc[i] = i32x4{0, 0, 0, 0};
  const int8_t* ha = Hall + (row0 + nn) * HID + q * 16;
  const uint4* wb = Wf8 + lane;
#pragma unroll
  for (int kt = 0; kt < 8; ++kt) {
    const i32x4 a = *(const i32x4*)(ha + kt * 64);
#pragma unroll
    for (int nt = 0; nt < 8; ++nt) {
      const i32x4 b = __builtin_bit_cast(i32x4, wb[(size_t)((32 + nt) * 8 + kt) * 64]);
      acc[nt] = __builtin_amdgcn_mfma_i32_16x16x64_i8(a, b, acc[nt], 0, 0, 0);
    }
  }
#pragma unroll
  for (int nt = 0; nt < 8; ++nt) {
    const float bo = b_o[nt * 16 + nn];
#pragma unroll
    for (int r = 0; r < 4; ++r)
      out[(row0 + q * 4 + r) * VOCAB + nt * 16 + nn] = (float)acc[nt][r] * f + bo;
  }
}

extern "C" void kernel_launch(void* const* d_in, const int* in_sizes, int n_in,
                              void* d_out, int out_size, void* d_ws, size_t ws_size,
                              hipStream_t stream) {
  const int*   x    = (const int*)d_in[0];
  const float* emb  = (const float*)d_in[1];
  const float* W_ih = (const float*)d_in[2];
  const float* b_ih = (const float*)d_in[3];
  const float* W_hh = (const float*)d_in[4];
  const float* b_hh = (const float*)d_in[5];
  const float* W_ho = (const float*)d_in[6];
  const float* b_o  = (const float*)d_in[7];
  float* out = (float*)d_out;

  char* ws = (char*)d_ws;
  float*        E      = (float*)ws;                        // 256 KB (E', permuted cols)
  uint4*        Wf8    = (uint4*)(ws + (256 << 10));        // 320 KB (40 nt x 8 x 1 KB)
  float*        scf    = (float*)(ws + 589824);             // [0..1] scales
  float*        parts  = scf + 2;                           // [0..39] abs-max partials
  int8_t*       Hall   = (int8_t*)(ws + (1 << 20));         // 64 MB i8 (k-permuted cols)

  prep_kernel<<<56, 512, 0, stream>>>(emb, W_ih, b_ih, b_hh, W_hh, W_ho, E, parts);
  pack8_kernel<<<320, 64, 0, stream>>>(W_hh, W_ho, parts, scf, Wf8);
  rnn_kernel<<<16, 512, 0, stream>>>(x, E, Wf8, scf, Hall,
                                     out + (size_t)BATCH * SEQ * VOCAB);
  ygemm_kernel<<<(BATCH * SEQ) / 64, 256, 0, stream>>>(Hall, Wf8, scf, b_o, out);
}